// Round 3
// baseline (326.221 us; speedup 1.0000x reference)
//
#include <hip/hip_runtime.h>
#include <hip/hip_bf16.h>
#include <math.h>

#define BB 32
#define LL 4096
#define HH 512
#define TM 64    // rows per block tile

typedef __attribute__((ext_vector_type(8))) short short8;
typedef __attribute__((ext_vector_type(8))) unsigned short u16x8;
typedef __attribute__((ext_vector_type(4))) float f32x4;

__device__ __forceinline__ unsigned short f2bf(float f) {
  __hip_bfloat16 h = __float2bfloat16(f);
  unsigned short u;
  __builtin_memcpy(&u, &h, 2);
  return u;
}
__device__ __forceinline__ float fast_tanh(float x) {
  float e = __expf(2.f * x);
  return 1.f - 2.f / (e + 1.f);
}

// ---------------------------------------------------------------------------
// prep_base: base[b][o] = query[b,:].Wq[o,:] + bias[o] + conv_b[o]
// ---------------------------------------------------------------------------
__global__ __launch_bounds__(256) void prep_base(
    const float* __restrict__ query, const float* __restrict__ Wq,
    const float* __restrict__ bias, const float* __restrict__ conv_b,
    float* __restrict__ base) {
  const int b = blockIdx.x >> 1;
  const int o = ((blockIdx.x & 1) << 8) + threadIdx.x;
  __shared__ float qrow[HH];
  for (int i = threadIdx.x; i < HH; i += 256) qrow[i] = query[b * HH + i];
  __syncthreads();
  const float* wq = Wq + (size_t)o * HH;
  float acc = 0.f;
  for (int h = 0; h < HH; h += 4) {
    float4 w = *(const float4*)(wq + h);
    acc += w.x * qrow[h] + w.y * qrow[h + 1] + w.z * qrow[h + 2] + w.w * qrow[h + 3];
  }
  base[b * HH + o] = acc + bias[o] + conv_b[o];
}

// ---------------------------------------------------------------------------
// prep_wv: Wv (f32 [o][h]) -> fragment-ordered bf16 (same as round 2)
// ---------------------------------------------------------------------------
__global__ __launch_bounds__(256) void prep_wv(const float* __restrict__ Wv,
                                               unsigned short* __restrict__ wvf) {
  const int chunk = blockIdx.x * 256 + threadIdx.x;
  const int l = chunk & 63;
  const int kk = (chunk >> 6) & 15;
  const int nb = chunk >> 10;
  const int row = nb * 16 + (l & 15);
  const int colf = kk * 32 + (l >> 4) * 8;
  const float* src = Wv + (size_t)row * HH + colf;
  u16x8 v;
  #pragma unroll
  for (int j = 0; j < 8; ++j) v[j] = f2bf(src[j]);
  *(u16x8*)(wvf + (size_t)chunk * 8) = v;
}

// ---------------------------------------------------------------------------
// main: block = (b, 64-row tile), 512 threads = 8 waves; wave w owns cols
// [w*64, w*64+64). NO LDS A-tile: A-fragments load directly from global
// (16 rows x 128B per wave-load = fully coalesced; L1-shared across waves).
// MFMA -> fused conv+tanh+Ws reduce -> sigmoid -> unnorm s -> context
// partials (value re-read from L1/L2) -> LDS reduce -> atomicAdd.
// grid (64, 32), block 512
// ---------------------------------------------------------------------------
__global__ __launch_bounds__(512, 4) void main_kernel(
    const float* __restrict__ value, const float* __restrict__ last_attn,
    const float* __restrict__ conv_w, const unsigned short* __restrict__ wvf,
    const float* __restrict__ Ws, const float* __restrict__ bs,
    const float* __restrict__ base, float* __restrict__ ctx,
    float* __restrict__ attn) {
  const int b = blockIdx.y;
  const int l0 = blockIdx.x * TM;
  const int tid = threadIdx.x;
  const int w = tid >> 6;
  const int lane = tid & 63;
  const int g = lane >> 4;
  const int r16 = lane & 15;

  __shared__ float la_s[TM + 2];
  __shared__ float scorered[8][TM];
  __shared__ float srow[TM];
  __shared__ float ctxred[8][HH];   // 16 KiB

  if (tid < TM + 2) {
    int l = l0 - 1 + tid;
    la_s[tid] = (l >= 0 && l < LL) ? last_attn[b * LL + l] : 0.f;
  }
  __syncthreads();

  // per-m A-fragment base pointers: row = l0 + m*16 + r16, col base = g*8
  const float* abase[4];
  #pragma unroll
  for (int m = 0; m < 4; ++m)
    abase[m] = value + (size_t)(b * LL + l0 + m * 16 + r16) * HH + g * 8;

  f32x4 acc[4][4] = {};

  short8 bcur[4], bnxt[4];
  #pragma unroll
  for (int n = 0; n < 4; ++n)
    bcur[n] = *(const short8*)(wvf + ((size_t)((w * 4 + n) * 16 + 0) * 64 + lane) * 8);

  for (int kk = 0; kk < 16; ++kk) {
    if (kk < 15) {
      #pragma unroll
      for (int n = 0; n < 4; ++n)
        bnxt[n] = *(const short8*)(wvf + ((size_t)((w * 4 + n) * 16 + kk + 1) * 64 + lane) * 8);
    }
    // batch-issue all 8 A loads (32 floats), then cvt, then MFMA
    float4 lo[4], hi[4];
    #pragma unroll
    for (int m = 0; m < 4; ++m) {
      const float* p = abase[m] + kk * 32;
      lo[m] = *(const float4*)(p);
      hi[m] = *(const float4*)(p + 4);
    }
    #pragma unroll
    for (int m = 0; m < 4; ++m) {
      short8 a;
      a[0] = (short)f2bf(lo[m].x); a[1] = (short)f2bf(lo[m].y);
      a[2] = (short)f2bf(lo[m].z); a[3] = (short)f2bf(lo[m].w);
      a[4] = (short)f2bf(hi[m].x); a[5] = (short)f2bf(hi[m].y);
      a[6] = (short)f2bf(hi[m].z); a[7] = (short)f2bf(hi[m].w);
      #pragma unroll
      for (int n = 0; n < 4; ++n)
        acc[m][n] = __builtin_amdgcn_mfma_f32_16x16x32_bf16(a, bcur[n], acc[m][n], 0, 0, 0);
    }
    #pragma unroll
    for (int n = 0; n < 4; ++n) bcur[n] = bnxt[n];
  }

  // ---- epilogue: e = tanh(acc + base + conv), rowsum += e*Ws ----
  float basev[4], wsv[4], cw0[4], cw1[4], cw2[4];
  #pragma unroll
  for (int n = 0; n < 4; ++n) {
    const int col = w * 64 + n * 16 + r16;
    basev[n] = base[b * HH + col];
    wsv[n] = Ws[col];
    cw0[n] = conv_w[col * 3 + 0];
    cw1[n] = conv_w[col * 3 + 1];
    cw2[n] = conv_w[col * 3 + 2];
  }
  #pragma unroll
  for (int m = 0; m < 4; ++m) {
    #pragma unroll
    for (int j = 0; j < 4; ++j) {
      const int row = m * 16 + g * 4 + j;
      const float lam = la_s[row], laz = la_s[row + 1], lap = la_s[row + 2];
      float sum = 0.f;
      #pragma unroll
      for (int n = 0; n < 4; ++n) {
        float e = acc[m][n][j] + basev[n] + cw0[n] * lam + cw1[n] * laz + cw2[n] * lap;
        sum += fast_tanh(e) * wsv[n];
      }
      sum += __shfl_xor(sum, 1, 64);
      sum += __shfl_xor(sum, 2, 64);
      sum += __shfl_xor(sum, 4, 64);
      sum += __shfl_xor(sum, 8, 64);
      if (r16 == 0) scorered[w][row] = sum;
    }
  }
  __syncthreads();
  if (tid < TM) {
    float sc = bs[0];
    #pragma unroll
    for (int ww = 0; ww < 8; ++ww) sc += scorered[ww][tid];
    float s = 1.f / (1.f + __expf(-sc));
    srow[tid] = s;
    attn[b * LL + l0 + tid] = s;   // unnormalized; finalize divides by S
  }
  __syncthreads();

  // ---- context partials: wave w covers rows w*8..w*8+8, lane owns 8 cols ----
  {
    float cs0 = 0.f, cs1 = 0.f, cs2 = 0.f, cs3 = 0.f;
    float cs4 = 0.f, cs5 = 0.f, cs6 = 0.f, cs7 = 0.f;
    #pragma unroll
    for (int i = 0; i < 8; ++i) {
      const int row = w * 8 + i;
      const float* p = value + (size_t)(b * LL + l0 + row) * HH + lane * 8;
      float4 lo = *(const float4*)(p);
      float4 hi = *(const float4*)(p + 4);
      const float s = srow[row];
      cs0 += s * lo.x; cs1 += s * lo.y; cs2 += s * lo.z; cs3 += s * lo.w;
      cs4 += s * hi.x; cs5 += s * hi.y; cs6 += s * hi.z; cs7 += s * hi.w;
    }
    float* r = &ctxred[w][lane * 8];
    r[0] = cs0; r[1] = cs1; r[2] = cs2; r[3] = cs3;
    r[4] = cs4; r[5] = cs5; r[6] = cs6; r[7] = cs7;
  }
  __syncthreads();
  {
    float sum = 0.f;
    #pragma unroll
    for (int ww = 0; ww < 8; ++ww) sum += ctxred[ww][tid];
    atomicAdd(&ctx[b * HH + tid], sum);
  }
}

// ---------------------------------------------------------------------------
// finalize: per batch: S = sum_l s; attn /= S; out = [ctx/S, query]
// ---------------------------------------------------------------------------
__global__ __launch_bounds__(512) void finalize_kernel(
    const float* __restrict__ query, const float* __restrict__ ctx,
    float* __restrict__ out, float* __restrict__ attn) {
  const int b = blockIdx.x;
  const int tid = threadIdx.x;
  __shared__ float red[8];
  float s = 0.f;
  for (int l = tid; l < LL; l += 512) s += attn[b * LL + l];
  #pragma unroll
  for (int off = 32; off > 0; off >>= 1) s += __shfl_xor(s, off, 64);
  if ((tid & 63) == 0) red[tid >> 6] = s;
  __syncthreads();
  float S = 0.f;
  #pragma unroll
  for (int i = 0; i < 8; ++i) S += red[i];
  const float inv = 1.f / S;
  out[b * 2 * HH + tid] = ctx[b * HH + tid] * inv;
  out[b * 2 * HH + HH + tid] = query[b * HH + tid];
  for (int l = tid; l < LL; l += 512) attn[b * LL + l] *= inv;
}

// ---------------------------------------------------------------------------
extern "C" void kernel_launch(void* const* d_in, const int* in_sizes, int n_in,
                              void* d_out, int out_size, void* d_ws, size_t ws_size,
                              hipStream_t stream) {
  const float* query     = (const float*)d_in[0];
  const float* value     = (const float*)d_in[1];
  const float* last_attn = (const float*)d_in[2];
  const float* conv_w    = (const float*)d_in[3];
  const float* conv_b    = (const float*)d_in[4];
  const float* Wq        = (const float*)d_in[5];
  const float* Wv        = (const float*)d_in[6];
  const float* Ws        = (const float*)d_in[7];
  const float* bs        = (const float*)d_in[8];
  const float* bias      = (const float*)d_in[9];

  float* out  = (float*)d_out;                 // (B, 2H)
  float* attn = out + BB * 2 * HH;             // (B, L)
  float* base = (float*)d_ws;                  // B*H f32
  float* ctx  = base + BB * HH;                // B*H f32 (atomic accum)
  unsigned short* wvf = (unsigned short*)(ctx + BB * HH);  // 512*512 bf16, frag-ordered

  hipMemsetAsync(ctx, 0, BB * HH * sizeof(float), stream);
  prep_base<<<64, 256, 0, stream>>>(query, Wq, bias, conv_b, base);
  prep_wv<<<128, 256, 0, stream>>>(Wv, wvf);
  dim3 grid(LL / TM, BB);
  main_kernel<<<grid, 512, 0, stream>>>(value, last_attn, conv_w, wvf, Ws, bs,
                                        base, ctx, attn);
  finalize_kernel<<<BB, 512, 0, stream>>>(query, ctx, out, attn);
}

// Round 4
// 185.332 us; speedup vs baseline: 1.7602x; 1.7602x over previous
//
#include <hip/hip_runtime.h>
#include <hip/hip_bf16.h>
#include <math.h>

#define BB 32
#define LL 4096
#define HH 512
#define TM 32    // rows per block tile

typedef __attribute__((ext_vector_type(8))) short short8;
typedef __attribute__((ext_vector_type(8))) unsigned short u16x8;
typedef __attribute__((ext_vector_type(4))) float f32x4;

__device__ __forceinline__ unsigned short f2bf(float f) {
  __hip_bfloat16 h = __float2bfloat16(f);
  unsigned short u;
  __builtin_memcpy(&u, &h, 2);
  return u;
}
__device__ __forceinline__ float bf2f(unsigned short u) {
  unsigned int x = ((unsigned int)u) << 16;
  float f;
  __builtin_memcpy(&f, &x, 4);
  return f;
}
__device__ __forceinline__ float fast_tanh(float x) {
  float e = __expf(2.f * x);
  return 1.f - 2.f / (e + 1.f);
}

// ---------------------------------------------------------------------------
// prep: fused {base + ctx-zero | wvf fragment pack}.
//  bid < 64 : base[b][o] = query[b,:].Wq[o,:] + bias[o] + conv_b[o]; ctx=0
//  bid >= 64: wvf[((nb*16+kk)*64+lane)*8+j] =
//             bf16(Wv[nb*16+(lane&15)][kk*32+(lane>>4)*8+j])
// grid 192, block 256
// ---------------------------------------------------------------------------
__global__ __launch_bounds__(256) void prep_kernel(
    const float* __restrict__ query, const float* __restrict__ Wq,
    const float* __restrict__ bias, const float* __restrict__ conv_b,
    const float* __restrict__ Wv, float* __restrict__ base,
    unsigned short* __restrict__ wvf, float* __restrict__ ctx) {
  const int bid = blockIdx.x;
  if (bid < 64) {
    const int b = bid >> 1;
    const int o = ((bid & 1) << 8) + threadIdx.x;
    __shared__ float qrow[HH];
    for (int i = threadIdx.x; i < HH; i += 256) qrow[i] = query[b * HH + i];
    __syncthreads();
    const float* wq = Wq + (size_t)o * HH;
    float acc = 0.f;
    for (int h = 0; h < HH; h += 4) {
      float4 w = *(const float4*)(wq + h);
      acc += w.x * qrow[h] + w.y * qrow[h + 1] + w.z * qrow[h + 2] + w.w * qrow[h + 3];
    }
    base[b * HH + o] = acc + bias[o] + conv_b[o];
    ctx[b * HH + o] = 0.f;
  } else {
    const int chunk = (bid - 64) * 256 + threadIdx.x;
    const int l = chunk & 63;
    const int kk = (chunk >> 6) & 15;
    const int nb = chunk >> 10;
    const int row = nb * 16 + (l & 15);
    const int colf = kk * 32 + (l >> 4) * 8;
    const float* src = Wv + (size_t)row * HH + colf;
    u16x8 v;
    #pragma unroll
    for (int j = 0; j < 8; ++j) v[j] = f2bf(src[j]);
    *(u16x8*)(wvf + (size_t)chunk * 8) = v;
  }
}

// ---------------------------------------------------------------------------
// main: block = (b, 32-row tile), 512 threads = 8 waves; wave w owns cols
// [w*64, w*64+64). Value tile staged bf16 in LDS (XOR-swizzled, 32 KiB).
// LDS total ~50 KiB -> 3 blocks/CU; __launch_bounds__(512,6) caps VGPR at 85
// so 24 waves/CU phase-stagger across 3 independent barrier domains.
// grid (128, 32), block 512
// ---------------------------------------------------------------------------
__global__ __launch_bounds__(512, 6) void main_kernel(
    const float* __restrict__ value, const float* __restrict__ last_attn,
    const float* __restrict__ conv_w, const unsigned short* __restrict__ wvf,
    const float* __restrict__ Ws, const float* __restrict__ bs,
    const float* __restrict__ base, float* __restrict__ ctx,
    float* __restrict__ attn) {
  const int b = blockIdx.y;
  const int l0 = blockIdx.x * TM;
  const int tid = threadIdx.x;
  const int w = tid >> 6;
  const int lane = tid & 63;
  const int g = lane >> 4;
  const int r16 = lane & 15;

  __shared__ __align__(16) unsigned short A[TM * HH];  // 32 KiB, swizzled
  __shared__ float la_s[TM + 2];
  __shared__ float scorered[8][TM];
  __shared__ float srow[TM];
  __shared__ float ctxred[8][HH];   // 16 KiB

  char* Ab = (char*)A;

  // ---- stage value tile: f32 -> bf16, swizzled LDS (4 chunks/thread) ----
  const float* vsrc = value + (size_t)(b * LL + l0) * HH;
  #pragma unroll
  for (int i = 0; i < 4; ++i) {
    const int c = tid + i * 512;        // 8-bf16 chunk index
    const int row = c >> 6;
    const int cb = c & 63;
    const float4* s4 = (const float4*)(vsrc + (size_t)row * HH + cb * 8);
    float4 lo = s4[0], hi = s4[1];
    u16x8 v;
    v[0] = f2bf(lo.x); v[1] = f2bf(lo.y); v[2] = f2bf(lo.z); v[3] = f2bf(lo.w);
    v[4] = f2bf(hi.x); v[5] = f2bf(hi.y); v[6] = f2bf(hi.z); v[7] = f2bf(hi.w);
    const int off = row * 1024 + ((cb * 16) ^ ((row & 7) << 4));
    *(u16x8*)(Ab + off) = v;
  }
  if (tid < TM + 2) {
    int l = l0 - 1 + tid;
    la_s[tid] = (l >= 0 && l < LL) ? last_attn[b * LL + l] : 0.f;
  }
  __syncthreads();

  // ---- MFMA: acc[m in 0..2][n in 0..4] over K=512 (16 steps) ----
  f32x4 acc[2][4] = {};
  #pragma unroll 2
  for (int kk = 0; kk < 16; ++kk) {
    const int co = kk * 64 + g * 16;
    const int row0 = r16, row1 = 16 + r16;
    short8 a0 = *(const short8*)(Ab + row0 * 1024 + (co ^ ((row0 & 7) << 4)));
    short8 a1 = *(const short8*)(Ab + row1 * 1024 + (co ^ ((row1 & 7) << 4)));
    #pragma unroll
    for (int n = 0; n < 4; ++n) {
      short8 bf = *(const short8*)(wvf + ((size_t)((w * 4 + n) * 16 + kk) * 64 + lane) * 8);
      acc[0][n] = __builtin_amdgcn_mfma_f32_16x16x32_bf16(a0, bf, acc[0][n], 0, 0, 0);
      acc[1][n] = __builtin_amdgcn_mfma_f32_16x16x32_bf16(a1, bf, acc[1][n], 0, 0, 0);
    }
  }

  // ---- epilogue: e = tanh(acc + base + conv), rowsum += e*Ws ----
  float basev[4], wsv[4], cw0[4], cw1[4], cw2[4];
  #pragma unroll
  for (int n = 0; n < 4; ++n) {
    const int col = w * 64 + n * 16 + r16;
    basev[n] = base[b * HH + col];
    wsv[n] = Ws[col];
    cw0[n] = conv_w[col * 3 + 0];
    cw1[n] = conv_w[col * 3 + 1];
    cw2[n] = conv_w[col * 3 + 2];
  }
  #pragma unroll
  for (int m = 0; m < 2; ++m) {
    #pragma unroll
    for (int j = 0; j < 4; ++j) {
      const int row = m * 16 + g * 4 + j;
      const float lam = la_s[row], laz = la_s[row + 1], lap = la_s[row + 2];
      float sum = 0.f;
      #pragma unroll
      for (int n = 0; n < 4; ++n) {
        float e = acc[m][n][j] + basev[n] + cw0[n] * lam + cw1[n] * laz + cw2[n] * lap;
        sum += fast_tanh(e) * wsv[n];
      }
      sum += __shfl_xor(sum, 1, 64);
      sum += __shfl_xor(sum, 2, 64);
      sum += __shfl_xor(sum, 4, 64);
      sum += __shfl_xor(sum, 8, 64);
      if (r16 == 0) scorered[w][row] = sum;
    }
  }
  __syncthreads();
  if (tid < TM) {
    float sc = bs[0];
    #pragma unroll
    for (int ww = 0; ww < 8; ++ww) sc += scorered[ww][tid];
    float s = 1.f / (1.f + __expf(-sc));
    srow[tid] = s;
    attn[b * LL + l0 + tid] = s;   // unnormalized; finalize divides by S
  }
  __syncthreads();

  // ---- context partials: wave w rows [w*4, w*4+4), lane owns 8 cols ----
  {
    float cs[8];
    #pragma unroll
    for (int k = 0; k < 8; ++k) cs[k] = 0.f;
    #pragma unroll
    for (int i = 0; i < 4; ++i) {
      const int row = w * 4 + i;
      const int off = row * 1024 + ((lane * 16) ^ ((row & 7) << 4));
      u16x8 v = *(const u16x8*)(Ab + off);
      const float s = srow[row];
      #pragma unroll
      for (int k = 0; k < 8; ++k) cs[k] += s * bf2f(v[k]);
    }
    float* r = &ctxred[w][lane * 8];
    #pragma unroll
    for (int k = 0; k < 8; ++k) r[k] = cs[k];
  }
  __syncthreads();
  {
    float sum = 0.f;
    #pragma unroll
    for (int ww = 0; ww < 8; ++ww) sum += ctxred[ww][tid];
    atomicAdd(&ctx[b * HH + tid], sum);
  }
}

// ---------------------------------------------------------------------------
// finalize: per batch: S = sum_l s; attn /= S; out = [ctx/S, query]
// grid B, block 512
// ---------------------------------------------------------------------------
__global__ __launch_bounds__(512) void finalize_kernel(
    const float* __restrict__ query, const float* __restrict__ ctx,
    float* __restrict__ out, float* __restrict__ attn) {
  const int b = blockIdx.x;
  const int tid = threadIdx.x;
  __shared__ float red[8];
  float s = 0.f;
  for (int l = tid; l < LL; l += 512) s += attn[b * LL + l];
  #pragma unroll
  for (int off = 32; off > 0; off >>= 1) s += __shfl_xor(s, off, 64);
  if ((tid & 63) == 0) red[tid >> 6] = s;
  __syncthreads();
  float S = 0.f;
  #pragma unroll
  for (int i = 0; i < 8; ++i) S += red[i];
  const float inv = 1.f / S;
  out[b * 2 * HH + tid] = ctx[b * HH + tid] * inv;
  out[b * 2 * HH + HH + tid] = query[b * HH + tid];
  for (int l = tid; l < LL; l += 512) attn[b * LL + l] *= inv;
}

// ---------------------------------------------------------------------------
extern "C" void kernel_launch(void* const* d_in, const int* in_sizes, int n_in,
                              void* d_out, int out_size, void* d_ws, size_t ws_size,
                              hipStream_t stream) {
  const float* query     = (const float*)d_in[0];
  const float* value     = (const float*)d_in[1];
  const float* last_attn = (const float*)d_in[2];
  const float* conv_w    = (const float*)d_in[3];
  const float* conv_b    = (const float*)d_in[4];
  const float* Wq        = (const float*)d_in[5];
  const float* Wv        = (const float*)d_in[6];
  const float* Ws        = (const float*)d_in[7];
  const float* bs        = (const float*)d_in[8];
  const float* bias      = (const float*)d_in[9];

  float* out  = (float*)d_out;                 // (B, 2H)
  float* attn = out + BB * 2 * HH;             // (B, L)
  float* base = (float*)d_ws;                  // B*H f32
  float* ctx  = base + BB * HH;                // B*H f32 (atomic accum)
  unsigned short* wvf = (unsigned short*)(ctx + BB * HH);  // 512*512 bf16, frag-ordered

  prep_kernel<<<192, 256, 0, stream>>>(query, Wq, bias, conv_b, Wv, base, wvf, ctx);
  dim3 grid(LL / TM, BB);
  main_kernel<<<grid, 512, 0, stream>>>(value, last_attn, conv_w, wvf, Ws, bs,
                                        base, ctx, attn);
  finalize_kernel<<<BB, 512, 0, stream>>>(query, ctx, out, attn);
}